// Round 3
// baseline (154.341 us; speedup 1.0000x reference)
//
#include <hip/hip_runtime.h>
#include <hip/hip_cooperative_groups.h>

namespace cg = cooperative_groups;

constexpr int B_ = 16;
constexpr int N_ = 500;
constexpr int NC = 10;
constexpr int FM_ = 360;
constexpr int RMAXC = 12;
constexpr long HM_ELEMS = (long)B_ * NC * FM_ * FM_;      // 20,736,000
constexpr long ANNO_OFF = HM_ELEMS;                        // +16*500*8 = 64,000
constexpr long IND_OFF  = ANNO_OFF + (long)B_ * N_ * 8;    // 20,800,000
constexpr long MASK_OFF = IND_OFF + (long)B_ * N_;         // 20,808,000
constexpr int GRID_BLKS = 512;

struct ObjParams {
    float cx_f, cy_f, sigma;
    int cx, cy, radius;
    bool valid;
};

// Replicates reference float32 op order exactly.
__device__ inline ObjParams compute_params(const float* bx) {
    float x = bx[0], y = bx[1];
    float w = bx[3], l = bx[4];
    ObjParams o;
    float wp = w / 0.075f / 4.0f;
    float lp = l / 0.075f / 4.0f;
    o.cx_f = (x + 54.0f) / 0.075f / 4.0f;   // (x - PCR0), PCR0 = -54.0
    o.cy_f = (y + 54.0f) / 0.075f / 4.0f;
    o.cx = (int)o.cx_f;                      // trunc == .astype(int32)
    o.cy = (int)o.cy_f;
    o.valid = (wp > 0.0f) && (lp > 0.0f) &&
              (o.cx >= 0) && (o.cx < FM_) && (o.cy >= 0) && (o.cy < FM_);
    // gaussian_radius(height=lp, width=wp, min_overlap=0.1)
    float height = lp, width = wp;
    float b1 = height + width;
    float c1 = width * height * 0.9f / 1.1f;
    float r1 = (b1 + sqrtf(b1 * b1 - 4.0f * c1)) / 2.0f;
    float b2 = 2.0f * (height + width);
    float c2 = 0.9f * width * height;
    float r2 = (b2 + sqrtf(b2 * b2 - 16.0f * c2)) / 2.0f;
    float b3 = -0.2f * (height + width);
    float c3 = -0.9f * width * height;
    float r3 = (b3 + sqrtf(b3 * b3 - 1.6f * c3)) / 2.0f;
    float r = fminf(fminf(r1, r2), r3);
    o.radius = max(2, (int)floorf(r));
    o.sigma = (2.0f * (float)o.radius + 1.0f) / 6.0f;
    return o;
}

__global__ __launch_bounds__(256, 2) void fused_kernel(
        const float* __restrict__ boxes, const int* __restrict__ labels,
        float* __restrict__ out) {
    int blk = blockIdx.x;
    int tid = threadIdx.x;
    __shared__ int lab[N_];

    if (blk < B_) {
        // ---- Phase 1a: stable rank by label + anno/ind/mask for batch `blk` ----
        int b = blk;
        for (int i = tid; i < N_; i += 256) lab[i] = labels[b * N_ + i];
        __syncthreads();
        for (int i = tid; i < N_; i += 256) {
            int c = lab[i];
            int rank = 0;
            #pragma unroll 4
            for (int j = 0; j < N_; ++j) {
                int lj = lab[j];
                rank += (lj < c) | ((lj == c) & (j < i));
            }
            const float* bx = boxes + (long)(b * N_ + i) * 9;
            ObjParams o = compute_params(bx);
            float* anno = out + ANNO_OFF + (long)(b * N_ + rank) * 8;
            if (o.valid) {
                float zz = bx[2], w = bx[3], l = bx[4], h = bx[5], rot = bx[8];
                float4 a0 = {o.cx_f - (float)o.cx, o.cy_f - (float)o.cy, zz, logf(w)};
                float4 a1 = {logf(l), logf(h), sinf(rot), cosf(rot)};
                *(float4*)anno = a0;
                *(float4*)(anno + 4) = a1;
                out[IND_OFF + b * N_ + rank]  = (float)(o.cy * FM_ + o.cx);
                out[MASK_OFF + b * N_ + rank] = 1.0f;
            } else {
                float4 z = {0.f, 0.f, 0.f, 0.f};
                *(float4*)anno = z;
                *(float4*)(anno + 4) = z;
                out[IND_OFF + b * N_ + rank]  = 0.0f;
                out[MASK_OFF + b * N_ + rank] = 0.0f;
            }
        }
    } else {
        // ---- Phase 1b: zero the heatmap region ----
        int zblk = blk - B_;
        constexpr int ZBLKS = GRID_BLKS - B_;
        float4* hm4 = (float4*)out;
        constexpr int n4 = (int)(HM_ELEMS / 4);
        float4 z = {0.f, 0.f, 0.f, 0.f};
        for (int k = zblk * 256 + tid; k < n4; k += ZBLKS * 256) hm4[k] = z;
    }

    __threadfence();                 // device-scope: zeros visible cross-XCD
    cg::this_grid().sync();

    // ---- Phase 2: gaussian window scatter-max, wave per object ----
    int wid = blk * 4 + (tid >> 6);
    int lane = tid & 63;
    for (int obj = wid; obj < B_ * N_; obj += GRID_BLKS * 4) {
        const float* bx = boxes + (long)obj * 9;
        ObjParams o = compute_params(bx);
        if (!o.valid) continue;
        int b = obj / N_;
        int cls = labels[obj] - 1;
        int reff = min(o.radius, RMAXC);
        int wsz = 2 * reff + 1;
        int total = wsz * wsz;
        float denom = 2.0f * (o.sigma * o.sigma);  // 2 * sigma**2, exact op order
        float* hm = out + ((long)b * NC + cls) * FM_ * FM_;
        for (int c = lane; c < total; c += 64) {
            int q = c / wsz;
            int dy = q - reff;
            int dx = c - q * wsz - reff;
            int yy = o.cy + dy, xx = o.cx + dx;
            if (yy < 0 || yy >= FM_ || xx < 0 || xx >= FM_) continue;
            float d2 = (float)(dx * dx + dy * dy);
            float g = expf(-d2 / denom);
            // g >= 0, heatmap init 0: int-view atomicMax preserves float order.
            atomicMax((int*)&hm[yy * FM_ + xx], __float_as_int(g));
        }
    }
}

extern "C" void kernel_launch(void* const* d_in, const int* in_sizes, int n_in,
                              void* d_out, int out_size, void* d_ws, size_t ws_size,
                              hipStream_t stream) {
    const float* boxes = (const float*)d_in[0];
    const int* labels  = (const int*)d_in[1];
    float* out = (float*)d_out;

    void* args[] = {(void*)&boxes, (void*)&labels, (void*)&out};
    hipLaunchCooperativeKernel((void*)fused_kernel, dim3(GRID_BLKS), dim3(256),
                               args, 0, stream);
}

// Round 4
// 30.845 us; speedup vs baseline: 5.0037x; 5.0037x over previous
//
#include <hip/hip_runtime.h>

constexpr int B_ = 16;
constexpr int N_ = 500;
constexpr int NC = 10;
constexpr int FM_ = 360;
constexpr int RMAXC = 12;
constexpr long HM_ELEMS = (long)B_ * NC * FM_ * FM_;      // 20,736,000
constexpr long ANNO_OFF = HM_ELEMS;                        // +16*500*8 = 64,000
constexpr long IND_OFF  = ANNO_OFF + (long)B_ * N_ * 8;    // 20,800,000
constexpr long MASK_OFF = IND_OFF + (long)B_ * N_;         // 20,808,000

constexpr int PREP_BLKS = 32;      // 2 blocks per batch
constexpr int ZERO_BLKS = 2048;

struct ObjParams {
    float cx_f, cy_f, sigma;
    int cx, cy, radius;
    bool valid;
};

// Replicates reference float32 op order exactly.
__device__ inline ObjParams compute_params(const float* bx) {
    float x = bx[0], y = bx[1];
    float w = bx[3], l = bx[4];
    ObjParams o;
    float wp = w / 0.075f / 4.0f;
    float lp = l / 0.075f / 4.0f;
    o.cx_f = (x + 54.0f) / 0.075f / 4.0f;   // (x - PCR0), PCR0 = -54.0
    o.cy_f = (y + 54.0f) / 0.075f / 4.0f;
    o.cx = (int)o.cx_f;                      // trunc == .astype(int32)
    o.cy = (int)o.cy_f;
    o.valid = (wp > 0.0f) && (lp > 0.0f) &&
              (o.cx >= 0) && (o.cx < FM_) && (o.cy >= 0) && (o.cy < FM_);
    // gaussian_radius(height=lp, width=wp, min_overlap=0.1)
    float height = lp, width = wp;
    float b1 = height + width;
    float c1 = width * height * 0.9f / 1.1f;
    float r1 = (b1 + sqrtf(b1 * b1 - 4.0f * c1)) / 2.0f;
    float b2 = 2.0f * (height + width);
    float c2 = 0.9f * width * height;
    float r2 = (b2 + sqrtf(b2 * b2 - 16.0f * c2)) / 2.0f;
    float b3 = -0.2f * (height + width);
    float c3 = -0.9f * width * height;
    float r3 = (b3 + sqrtf(b3 * b3 - 1.6f * c3)) / 2.0f;
    float r = fminf(fminf(r1, r2), r3);
    o.radius = max(2, (int)floorf(r));
    o.sigma = (2.0f * (float)o.radius + 1.0f) / 6.0f;
    return o;
}

// Kernel A: blocks [0,PREP_BLKS) do rank + anno/ind/mask (tiny); the rest
// zero the 83 MB heatmap. Disjoint output regions -> no sync needed.
__global__ __launch_bounds__(256) void prep_zero_kernel(
        const float* __restrict__ boxes, const int* __restrict__ labels,
        float* __restrict__ out) {
    int blk = blockIdx.x;
    int tid = threadIdx.x;

    if (blk < PREP_BLKS) {
        int b = blk >> 1;
        int half = blk & 1;
        __shared__ int lab[N_];
        for (int k = tid; k < N_; k += 256) lab[k] = labels[b * N_ + k];
        __syncthreads();
        int i = half * 250 + tid;
        if (tid < 250) {
            // stable rank: #(lab[j] < c) + #(j < i: lab[j] == c)
            int c = lab[i];
            int rank = 0;
            #pragma unroll 8
            for (int j = 0; j < N_; ++j) {
                int lj = lab[j];
                rank += (lj < c) | ((lj == c) & (j < i));
            }
            const float* bx = boxes + (long)(b * N_ + i) * 9;
            ObjParams o = compute_params(bx);
            float* anno = out + ANNO_OFF + (long)(b * N_ + rank) * 8;
            if (o.valid) {
                float zz = bx[2], w = bx[3], l = bx[4], h = bx[5], rot = bx[8];
                float4 a0 = {o.cx_f - (float)o.cx, o.cy_f - (float)o.cy, zz, logf(w)};
                float4 a1 = {logf(l), logf(h), sinf(rot), cosf(rot)};
                *(float4*)anno = a0;
                *(float4*)(anno + 4) = a1;
                out[IND_OFF + b * N_ + rank]  = (float)(o.cy * FM_ + o.cx);
                out[MASK_OFF + b * N_ + rank] = 1.0f;
            } else {
                float4 z = {0.f, 0.f, 0.f, 0.f};
                *(float4*)anno = z;
                *(float4*)(anno + 4) = z;
                out[IND_OFF + b * N_ + rank]  = 0.0f;
                out[MASK_OFF + b * N_ + rank] = 0.0f;
            }
        }
    } else {
        int zblk = blk - PREP_BLKS;
        float4* hm4 = (float4*)out;
        constexpr int n4 = (int)(HM_ELEMS / 4);
        float4 z = {0.f, 0.f, 0.f, 0.f};
        for (int k = zblk * 256 + tid; k < n4; k += ZERO_BLKS * 256) hm4[k] = z;
    }
}

// Kernel B: gaussian window scatter-max, one wave per object (8000 waves).
__global__ __launch_bounds__(256) void scatter_kernel(
        const float* __restrict__ boxes, const int* __restrict__ labels,
        float* __restrict__ out) {
    int obj = blockIdx.x * 4 + (threadIdx.x >> 6);   // 0 .. B*N-1
    int lane = threadIdx.x & 63;
    const float* bx = boxes + (long)obj * 9;
    ObjParams o = compute_params(bx);
    if (!o.valid) return;
    int b = obj / N_;
    int cls = labels[obj] - 1;
    int reff = min(o.radius, RMAXC);
    int wsz = 2 * reff + 1;
    int total = wsz * wsz;
    float denom = 2.0f * (o.sigma * o.sigma);        // 2 * sigma**2, exact op order
    float* hm = out + ((long)b * NC + cls) * FM_ * FM_;
    for (int c = lane; c < total; c += 64) {
        int q = c / wsz;
        int dy = q - reff;
        int dx = c - q * wsz - reff;
        int yy = o.cy + dy, xx = o.cx + dx;
        if (yy < 0 || yy >= FM_ || xx < 0 || xx >= FM_) continue;
        float d2 = (float)(dx * dx + dy * dy);
        float g = expf(-d2 / denom);
        // g >= 0, heatmap init 0: int-view atomicMax preserves float order.
        atomicMax((int*)&hm[yy * FM_ + xx], __float_as_int(g));
    }
}

extern "C" void kernel_launch(void* const* d_in, const int* in_sizes, int n_in,
                              void* d_out, int out_size, void* d_ws, size_t ws_size,
                              hipStream_t stream) {
    const float* boxes = (const float*)d_in[0];
    const int* labels  = (const int*)d_in[1];
    float* out = (float*)d_out;

    prep_zero_kernel<<<PREP_BLKS + ZERO_BLKS, 256, 0, stream>>>(boxes, labels, out);
    scatter_kernel<<<(B_ * N_) / 4, 256, 0, stream>>>(boxes, labels, out);
}